// Round 12
// baseline (162.231 us; speedup 1.0000x reference)
//
#include <hip/hip_runtime.h>

#define B_ 8
#define T_ 2048
#define H_ 256
#define PSTR 40                  // P LDS row stride (elems): 32+8
#define SCALE2 0.0901684403f     // (1/16) * log2(e)
#define SLOPE2 0.00563552752f    // 2^-8 * log2(e)
#define ELEMS ((size_t)B_ * T_ * H_)

typedef __attribute__((ext_vector_type(8))) short bf16x8;
typedef __attribute__((ext_vector_type(4))) float f32x4;

#define MFMA16(a, b, c) __builtin_amdgcn_mfma_f32_16x16x32_bf16((a), (b), (c), 0, 0, 0)

__device__ __forceinline__ ushort f2bf(float f) {
  unsigned u = __float_as_uint(f);
  u += 0x7FFFu + ((u >> 16) & 1u);   // RNE; finite inputs
  return (ushort)(u >> 16);
}

// async 16B/lane global->LDS DMA (contiguous: LDS = uniform base + lane*16)
__device__ __forceinline__ void gl_lds16(const ushort* g, ushort* l) {
  __builtin_amdgcn_global_load_lds(
      (const __attribute__((address_space(1))) unsigned int*)g,
      (__attribute__((address_space(3))) unsigned int*)l, 16, 0, 0);
}

// ---- prologue: blocks [0,1024) RoPE(k)->bf16 blocked ktile; [1024,2048) v transpose ----
// ktile layout: [b][it=t/32][d8=d/8][kv=t%32][8]   (16KB contiguous per (b,it) tile)
// vtile layout: [b][it][kvq=(t%32)/8][h][8]
__global__ void prep_kernel(const float* __restrict__ k, const float* __restrict__ v,
                            ushort* __restrict__ kt, ushort* __restrict__ vt) {
  __shared__ ushort tile[64][72];
  const int bid = blockIdx.x;
  const int tid = threadIdx.x;
  if (bid < 1024) {
    // K RoPE: thread = (bt, d8); reads 2x32B coalesced, writes 2x16B vector stores
    int idx = bid * 256 + tid;          // over B*T*16
    int d8 = idx & 15;
    int bt = idx >> 4;
    int t = bt & (T_ - 1);
    int b = bt >> 11;
    size_t base = (size_t)bt * H_ + d8 * 8;
    float4 a0 = *(const float4*)(k + base);
    float4 a1 = *(const float4*)(k + base + 4);
    float4 c0 = *(const float4*)(k + base + 128);
    float4 c1 = *(const float4*)(k + base + 132);
    float av[8] = {a0.x, a0.y, a0.z, a0.w, a1.x, a1.y, a1.z, a1.w};
    float cv[8] = {c0.x, c0.y, c0.z, c0.w, c1.x, c1.y, c1.z, c1.w};
    bf16x8 lo, hi;
#pragma unroll
    for (int e = 0; e < 8; ++e) {
      int j = d8 * 8 + e;
      float rv = (float)t * exp2f((float)j * -0.103810252959f) * 0.15915494309f;
      float fr = rv - floorf(rv);
      float sn = __builtin_amdgcn_sinf(fr), cs = __builtin_amdgcn_cosf(fr);
      lo[e] = (short)f2bf(av[e] * cs - cv[e] * sn);
      hi[e] = (short)f2bf(cv[e] * cs + av[e] * sn);
    }
    size_t kdst = (((size_t)(b * 64 + (t >> 5)) * 32 + d8) * 32 + (t & 31)) * 8;
    *(bf16x8*)(kt + kdst) = lo;
    *(bf16x8*)(kt + kdst + 4096) = hi;   // d8 + 16
  } else {
    // V transpose into blocked vtile, 64x64 tiles, XOR-8 swizzle in LDS
    int bid2 = bid - 1024;
    int b = bid2 >> 7, rem = bid2 & 127;
    int h0 = (rem >> 5) * 64, t0 = (rem & 31) * 64;
    int c4 = tid & 15, r0 = tid >> 4;
#pragma unroll
    for (int p = 0; p < 4; ++p) {
      int row = r0 + p * 16;
      const float4 f = *(const float4*)(v + ((size_t)(b * T_ + t0 + row)) * H_ + h0 + c4 * 4);
      ushort4 u;
      u.x = f2bf(f.x); u.y = f2bf(f.y); u.z = f2bf(f.z); u.w = f2bf(f.w);
      *(ushort4*)&tile[row][(c4 * 4) ^ (8 * ((row >> 3) & 7))] = u;
    }
    __syncthreads();
#pragma unroll
    for (int p = 0; p < 2; ++p) {
      int c = tid + p * 256;
      int h = c >> 3, tc = (c & 7) * 8;
      int xo = 8 * (c & 7);
      ushort4 u0, u1;
      u0.x = tile[tc + 0][h ^ xo]; u0.y = tile[tc + 1][h ^ xo];
      u0.z = tile[tc + 2][h ^ xo]; u0.w = tile[tc + 3][h ^ xo];
      u1.x = tile[tc + 4][h ^ xo]; u1.y = tile[tc + 5][h ^ xo];
      u1.z = tile[tc + 6][h ^ xo]; u1.w = tile[tc + 7][h ^ xo];
      int tg = t0 + tc;
      size_t dst = (((size_t)(b * 64 + (tg >> 5)) * 4 + ((tg >> 3) & 3)) * 256 + (h0 + h)) * 8;
      *(ushort4*)(vt + dst) = u0;
      *(ushort4*)(vt + dst + 4) = u1;
    }
  }
}

// ---- Flash attention: SMALL independent blocks for phase mixing.
// 256 thr = 4 waves x 16 q-rows (q-tile 64), KVBLK=32, kv-split S=gridDim.z
// (4 -> grid (8,32,4) = 1024 blocks = 4 blocks/CU = 8 waves/SIMD, with each
// SIMD hosting waves from 4 INDEPENDENT barrier domains: one block's QK
// (MFMA) overlaps another's softmax (VALU) and a third's DMA wait).
// K and V SINGLE-buffered (37 KB LDS): per-chain iteration is fully serial
// (vmcnt(0) acquire; DMA for it+1 issued after the release barrier) —
// latency is hidden by the other resident blocks, not by ILP.
__global__ __launch_bounds__(256, 4)
void attn_kernel(const float* __restrict__ q, const ushort* __restrict__ kt,
                 const ushort* __restrict__ vt, float* __restrict__ out,
                 float* __restrict__ opart, float* __restrict__ lpart) {
  __shared__ ushort Ksh[8192];          // [d8][kv32][8]  16 KB
  __shared__ ushort Vsh[8192];          // [kvq][h256][8] 16 KB
  __shared__ ushort Psh[4][16 * PSTR];  // per-wave P      5 KB

  const int tid = threadIdx.x;
  const int w = tid >> 6, lane = tid & 63, quad = lane >> 4, l16 = lane & 15;
  const int b = blockIdx.x;             // linear%8==b -> XCD affinity
  const int q0 = blockIdx.y * 64;
  const int sp = blockIdx.z;
  const int S = gridDim.z;
  const int niter = (T_ / 32) / S;
  const int kvb = sp * (T_ / S);

  // ---- in-register RoPE of this wave's 16 Q rows into A-frags ----
  bf16x8 aq[8];
  {
    const float* qb = q + ((size_t)(b * T_) + q0 + w * 16) * H_;
    const int t = q0 + w * 16 + l16;
    float qv[8][8];
#pragma unroll
    for (int ks = 0; ks < 8; ++ks) {
      float4 x0 = *(const float4*)(qb + (size_t)l16 * H_ + ks * 32 + quad * 8);
      float4 x1 = *(const float4*)(qb + (size_t)l16 * H_ + ks * 32 + quad * 8 + 4);
      qv[ks][0] = x0.x; qv[ks][1] = x0.y; qv[ks][2] = x0.z; qv[ks][3] = x0.w;
      qv[ks][4] = x1.x; qv[ks][5] = x1.y; qv[ks][6] = x1.z; qv[ks][7] = x1.w;
    }
#pragma unroll
    for (int ks = 0; ks < 4; ++ks)
#pragma unroll
      for (int e = 0; e < 8; ++e) {
        int d = ks * 32 + quad * 8 + e;
        float rv = (float)t * exp2f((float)d * -0.103810252959f) * 0.15915494309f;
        float fr = rv - floorf(rv);
        float sn = __builtin_amdgcn_sinf(fr), cs = __builtin_amdgcn_cosf(fr);
        aq[ks][e]     = (short)f2bf(qv[ks][e] * cs - qv[ks + 4][e] * sn);
        aq[ks + 4][e] = (short)f2bf(qv[ks + 4][e] * cs + qv[ks][e] * sn);
      }
  }

  const f32x4 fzero = {0.f, 0.f, 0.f, 0.f};
  f32x4 O[16], lac = fzero;
#pragma unroll
  for (int ht = 0; ht < 16; ++ht) O[ht] = fzero;
  bf16x8 vones;
#pragma unroll
  for (int i = 0; i < 8; ++i) vones[i] = (short)0x3F80;

  // this split's stream: 64/S 16KB-subtiles starting at sp*(64/S)
  const ushort* ktb = kt + (size_t)(b * 64 + sp * (64 / S)) * 8192;
  const ushort* vtb = vt + (size_t)(b * 64 + sp * (64 / S)) * 8192;
  const int stoff = tid * 8;            // 16B/lane over 256 threads = 4KB/round

  // issue tile 0 DMA (4 K + 4 V per thread)
#pragma unroll
  for (int i = 0; i < 4; ++i) {
    gl_lds16(ktb + stoff + i * 2048, &Ksh[stoff + i * 2048]);
    gl_lds16(vtb + stoff + i * 2048, &Vsh[stoff + i * 2048]);
  }

  const float arb = SLOPE2 * (float)(q0 + w * 16 + quad * 4);

  for (int it = 0; it < niter; ++it) {
    // acquire: this iter's 8 DMAs (issued last iter / prologue) must land
    __builtin_amdgcn_sched_barrier(0);
    __builtin_amdgcn_s_waitcnt(0x0F70);   // vmcnt(0)
    __builtin_amdgcn_s_barrier();
    __builtin_amdgcn_sched_barrier(0);

    // QK on Ksh
    f32x4 s[2] = {fzero, fzero};
#pragma unroll
    for (int ks = 0; ks < 8; ++ks)
#pragma unroll
      for (int nt = 0; nt < 2; ++nt) {
        bf16x8 kf = *(const bf16x8*)&Ksh[((ks * 4 + quad) * 32 + nt * 16 + l16) * 8];
        s[nt] = MFMA16(aq[ks], kf, s[nt]);
      }

    // p = exp2(s*SCALE2 + SLOPE2*(col-row)) -> wave-private Psh
#pragma unroll
    for (int nt = 0; nt < 2; ++nt) {
      float ac = SLOPE2 * (float)(kvb + it * 32 + nt * 16 + l16);
#pragma unroll
      for (int r = 0; r < 4; ++r) {
        float a0 = ac - arb - SLOPE2 * (float)r;
        float pv = __builtin_amdgcn_exp2f(fmaf(s[nt][r], SCALE2, a0));
        Psh[w][(quad * 4 + r) * PSTR + nt * 16 + l16] = f2bf(pv);
      }
    }

    // PV + rowsum via ones-MFMA (lgkmcnt orders the wave-private write->read)
    bf16x8 pf = *(const bf16x8*)&Psh[w][l16 * PSTR + quad * 8];
    lac = MFMA16(pf, vones, lac);
#pragma unroll
    for (int ht = 0; ht < 16; ++ht) {
      bf16x8 vf = *(const bf16x8*)&Vsh[(quad * 256 + ht * 16 + l16) * 8];
      O[ht] = MFMA16(pf, vf, O[ht]);
    }

    // release: all waves' LDS reads retired -> buffers may be overwritten
    __builtin_amdgcn_sched_barrier(0);
    __builtin_amdgcn_s_waitcnt(0xC07F);   // lgkmcnt(0) only
    __builtin_amdgcn_s_barrier();
    __builtin_amdgcn_sched_barrier(0);

    // issue DMA for tile(it+1); waited at next acquire. Latency is hidden
    // by the 3 other resident blocks on this CU, not by this chain.
    if (it < niter - 1) {
      const ushort* kg = ktb + (size_t)(it + 1) * 8192;
      const ushort* vg = vtb + (size_t)(it + 1) * 8192;
#pragma unroll
      for (int i = 0; i < 4; ++i) {
        gl_lds16(kg + stoff + i * 2048, &Ksh[stoff + i * 2048]);
        gl_lds16(vg + stoff + i * 2048, &Vsh[stoff + i * 2048]);
      }
    }
  }

  // epilogue: unnormalized O-partial + l-partial
  float* od = (sp == 0) ? out : (opart + (size_t)(sp - 1) * ELEMS);
  float* ob = od + ((size_t)(b * T_) + q0 + w * 16) * H_;
#pragma unroll
  for (int r = 0; r < 4; ++r) {
    int row = quad * 4 + r;
#pragma unroll
    for (int ht = 0; ht < 16; ++ht)
      ob[(size_t)row * H_ + ht * 16 + l16] = O[ht][r];
  }
  if (l16 == 0) {
#pragma unroll
    for (int r = 0; r < 4; ++r)
      lpart[(size_t)(sp * B_ + b) * T_ + q0 + w * 16 + quad * 4 + r] = lac[r];
  }
}

// ---- combine: out = (O0 + ... + O_{S-1}) / (l0 + ... + l_{S-1}) ----
__global__ void combine_kernel(float* __restrict__ out, const float* __restrict__ opart,
                               const float* __restrict__ lpart, int S) {
  int idx = blockIdx.x * 256 + threadIdx.x;   // over B*T*H/4
  int row = idx >> 6;
  float l = lpart[row];
  for (int s = 1; s < S; ++s) l += lpart[(size_t)s * B_ * T_ + row];
  float inv = 1.0f / l;
  float4 a = ((const float4*)out)[idx];
  for (int s = 1; s < S; ++s) {
    float4 c = ((const float4*)opart)[(size_t)(s - 1) * (ELEMS / 4) + idx];
    a.x += c.x; a.y += c.y; a.z += c.z; a.w += c.w;
  }
  a.x *= inv; a.y *= inv; a.z *= inv; a.w *= inv;
  ((float4*)out)[idx] = a;
}

extern "C" void kernel_launch(void* const* d_in, const int* in_sizes, int n_in,
                              void* d_out, int out_size, void* d_ws, size_t ws_size,
                              hipStream_t stream) {
  const float* q = (const float*)d_in[0];
  const float* k = (const float*)d_in[1];
  const float* v = (const float*)d_in[2];
  float* out = (float*)d_out;

  ushort* kt = (ushort*)d_ws;
  ushort* vt = kt + ELEMS;
  float* opart = (float*)(vt + ELEMS);
  // S=4 needs: kt+vt (2*ELEMS*2B) + 3 opart (3*ELEMS*4B) + lpart (4*B*T*4B)
  const size_t need4 = ELEMS * 4 + 3 * ELEMS * 4 + (size_t)4 * B_ * T_ * 4;
  const int S = (ws_size >= need4) ? 4 : 2;
  float* lpart = opart + (size_t)(S - 1) * ELEMS;

  prep_kernel<<<dim3(2048), 256, 0, stream>>>(k, v, kt, vt);
  attn_kernel<<<dim3(B_, T_ / 64, S), 256, 0, stream>>>(q, kt, vt, out, opart, lpart);
  combine_kernel<<<dim3((B_ * T_ * H_ / 4) / 256), 256, 0, stream>>>(out, opart, lpart, S);
}

// Round 14
// 144.940 us; speedup vs baseline: 1.1193x; 1.1193x over previous
//
#include <hip/hip_runtime.h>

#define B_ 8
#define T_ 2048
#define H_ 256
#define PSTR 72                  // P LDS row stride (elems), 64+8 pad
#define SCALE2 0.0901684403f     // (1/16) * log2(e)
#define SLOPE2 0.00563552752f    // 2^-8 * log2(e)
#define ELEMS ((size_t)B_ * T_ * H_)

typedef __attribute__((ext_vector_type(8))) short bf16x8;
typedef __attribute__((ext_vector_type(4))) float f32x4;

#define MFMA16(a, b, c) __builtin_amdgcn_mfma_f32_16x16x32_bf16((a), (b), (c), 0, 0, 0)

__device__ __forceinline__ ushort f2bf(float f) {
  unsigned u = __float_as_uint(f);
  u += 0x7FFFu + ((u >> 16) & 1u);   // RNE; finite inputs
  return (ushort)(u >> 16);
}

// async 16B/lane global->LDS DMA (contiguous: LDS = uniform base + lane*16)
__device__ __forceinline__ void gl_lds16(const ushort* g, ushort* l) {
  __builtin_amdgcn_global_load_lds(
      (const __attribute__((address_space(1))) unsigned int*)g,
      (__attribute__((address_space(3))) unsigned int*)l, 16, 0, 0);
}

// ---- prologue: blocks [0,1024) RoPE(k)->bf16 blocked ktile; [1024,2048) v transpose ----
// ktile layout: [b][it=t/32][d8=d/8][kv=t%32][8]   (16KB contiguous per (b,it) tile)
// vtile layout: [b][it][kvq=(t%32)/8][h][8]
__global__ void prep_kernel(const float* __restrict__ k, const float* __restrict__ v,
                            ushort* __restrict__ kt, ushort* __restrict__ vt) {
  __shared__ ushort tile[64][72];
  const int bid = blockIdx.x;
  const int tid = threadIdx.x;
  if (bid < 1024) {
    // K RoPE: thread = (bt, d8); reads 2x32B coalesced, writes 2x16B vector stores
    int idx = bid * 256 + tid;          // over B*T*16
    int d8 = idx & 15;
    int bt = idx >> 4;
    int t = bt & (T_ - 1);
    int b = bt >> 11;
    size_t base = (size_t)bt * H_ + d8 * 8;
    float4 a0 = *(const float4*)(k + base);
    float4 a1 = *(const float4*)(k + base + 4);
    float4 c0 = *(const float4*)(k + base + 128);
    float4 c1 = *(const float4*)(k + base + 132);
    float av[8] = {a0.x, a0.y, a0.z, a0.w, a1.x, a1.y, a1.z, a1.w};
    float cv[8] = {c0.x, c0.y, c0.z, c0.w, c1.x, c1.y, c1.z, c1.w};
    bf16x8 lo, hi;
#pragma unroll
    for (int e = 0; e < 8; ++e) {
      int j = d8 * 8 + e;
      float rv = (float)t * exp2f((float)j * -0.103810252959f) * 0.15915494309f;
      float fr = rv - floorf(rv);
      float sn = __builtin_amdgcn_sinf(fr), cs = __builtin_amdgcn_cosf(fr);
      lo[e] = (short)f2bf(av[e] * cs - cv[e] * sn);
      hi[e] = (short)f2bf(cv[e] * cs + av[e] * sn);
    }
    size_t kdst = (((size_t)(b * 64 + (t >> 5)) * 32 + d8) * 32 + (t & 31)) * 8;
    *(bf16x8*)(kt + kdst) = lo;
    *(bf16x8*)(kt + kdst + 4096) = hi;   // d8 + 16
  } else {
    // V transpose into blocked vtile, 64x64 tiles, XOR-8 swizzle in LDS
    int bid2 = bid - 1024;
    int b = bid2 >> 7, rem = bid2 & 127;
    int h0 = (rem >> 5) * 64, t0 = (rem & 31) * 64;
    int c4 = tid & 15, r0 = tid >> 4;
#pragma unroll
    for (int p = 0; p < 4; ++p) {
      int row = r0 + p * 16;
      const float4 f = *(const float4*)(v + ((size_t)(b * T_ + t0 + row)) * H_ + h0 + c4 * 4);
      ushort4 u;
      u.x = f2bf(f.x); u.y = f2bf(f.y); u.z = f2bf(f.z); u.w = f2bf(f.w);
      *(ushort4*)&tile[row][(c4 * 4) ^ (8 * ((row >> 3) & 7))] = u;
    }
    __syncthreads();
#pragma unroll
    for (int p = 0; p < 2; ++p) {
      int c = tid + p * 256;
      int h = c >> 3, tc = (c & 7) * 8;
      int xo = 8 * (c & 7);
      ushort4 u0, u1;
      u0.x = tile[tc + 0][h ^ xo]; u0.y = tile[tc + 1][h ^ xo];
      u0.z = tile[tc + 2][h ^ xo]; u0.w = tile[tc + 3][h ^ xo];
      u1.x = tile[tc + 4][h ^ xo]; u1.y = tile[tc + 5][h ^ xo];
      u1.z = tile[tc + 6][h ^ xo]; u1.w = tile[tc + 7][h ^ xo];
      int tg = t0 + tc;
      size_t dst = (((size_t)(b * 64 + (tg >> 5)) * 4 + ((tg >> 3) & 3)) * 256 + (h0 + h)) * 8;
      *(ushort4*)(vt + dst) = u0;
      *(ushort4*)(vt + dst + 4) = u1;
    }
  }
}

// ---- Flash attention: R8 (KVBLK=64, S=2, 8 waves x 16 q-rows) with T15
// cross-iteration pipelining: QK(it) and softmax+PV(it-1) are independent
// register streams in the same region -> PV MFMAs issue without waiting on
// this iter's QK->softmax chain; softmax VALU fills the QK MFMA shadow.
// Buffering: K prefetch distance 2 (dbuf), V distance 1 (dbuf; V(it) is
// consumed by PV(it) during iter it+1, V(it+1) issued at end of iter it).
// vmcnt queue at acquire(it): [K(it):4, V(it-1):4, K(it+1):4, V(it):4]
// -> single vmcnt(8) covers K(it)+V(it-1). Last acquire: vmcnt(4).
// LDS 146 KB (same as R8), 2 barriers/iter, 2 waves/SIMD: clean A/B vs R8.
__global__ __launch_bounds__(512, 2)
void attn_kernel(const float* __restrict__ q, const ushort* __restrict__ kt,
                 const ushort* __restrict__ vt, float* __restrict__ out,
                 float* __restrict__ o1, float* __restrict__ lpart) {
  __shared__ ushort Ksh[2][16384];      // [buf][half][d8][kv32][8]  64 KB
  __shared__ ushort Vsh[2][16384];      // [buf][half][kvq][h256][8] 64 KB
  __shared__ ushort Psh[8][16 * PSTR];  // per-wave P [16 rows][64+8] 18 KB

  const int tid = threadIdx.x;
  const int w = tid >> 6, lane = tid & 63, quad = lane >> 4, l16 = lane & 15;
  const int b = blockIdx.x;             // linear%8==b -> XCD affinity
  const int q0 = blockIdx.y * 128;
  const int sp = blockIdx.z;
  const int kvb = sp * (T_ / 2);
  const int niter = 16;                 // (T/2)/64

  // ---- in-register RoPE of this wave's 16 Q rows into A-frags ----
  bf16x8 aq[8];
  {
    const float* qb = q + ((size_t)(b * T_) + q0 + w * 16) * H_;
    const int t = q0 + w * 16 + l16;
    float qv[8][8];
#pragma unroll
    for (int ks = 0; ks < 8; ++ks) {
      float4 x0 = *(const float4*)(qb + (size_t)l16 * H_ + ks * 32 + quad * 8);
      float4 x1 = *(const float4*)(qb + (size_t)l16 * H_ + ks * 32 + quad * 8 + 4);
      qv[ks][0] = x0.x; qv[ks][1] = x0.y; qv[ks][2] = x0.z; qv[ks][3] = x0.w;
      qv[ks][4] = x1.x; qv[ks][5] = x1.y; qv[ks][6] = x1.z; qv[ks][7] = x1.w;
    }
#pragma unroll
    for (int ks = 0; ks < 4; ++ks)
#pragma unroll
      for (int e = 0; e < 8; ++e) {
        int d = ks * 32 + quad * 8 + e;
        float rv = (float)t * exp2f((float)d * -0.103810252959f) * 0.15915494309f;
        float fr = rv - floorf(rv);
        float sn = __builtin_amdgcn_sinf(fr), cs = __builtin_amdgcn_cosf(fr);
        aq[ks][e]     = (short)f2bf(qv[ks][e] * cs - qv[ks + 4][e] * sn);
        aq[ks + 4][e] = (short)f2bf(qv[ks + 4][e] * cs + qv[ks][e] * sn);
      }
  }

  const f32x4 fzero = {0.f, 0.f, 0.f, 0.f};
  f32x4 O[16], lac = fzero;
#pragma unroll
  for (int ht = 0; ht < 16; ++ht) O[ht] = fzero;
  bf16x8 vones;
#pragma unroll
  for (int i = 0; i < 8; ++i) vones[i] = (short)0x3F80;

  const ushort* ktb = kt + (size_t)(b * 64 + sp * 32) * 8192;
  const ushort* vtb = vt + (size_t)(b * 64 + sp * 32) * 8192;
  const int stoff = tid * 8;            // 16B/lane over 512 threads = 8KB/DMA

  // prologue issue order pins the ledger: K0(4), K1(4), V0(4)
#pragma unroll
  for (int i = 0; i < 4; ++i)
    gl_lds16(ktb + stoff + i * 4096, &Ksh[0][stoff + i * 4096]);
  __builtin_amdgcn_sched_barrier(0);
#pragma unroll
  for (int i = 0; i < 4; ++i)
    gl_lds16(ktb + 16384 + stoff + i * 4096, &Ksh[1][stoff + i * 4096]);
  __builtin_amdgcn_sched_barrier(0);
#pragma unroll
  for (int i = 0; i < 4; ++i)
    gl_lds16(vtb + stoff + i * 4096, &Vsh[0][stoff + i * 4096]);

  const float arb = SLOPE2 * (float)(q0 + w * 16 + quad * 4);
  f32x4 s_prev[4] = {fzero, fzero, fzero, fzero};

  // ---- peeled iter 0: QK(0) only ----
  {
    __builtin_amdgcn_sched_barrier(0);
    __builtin_amdgcn_s_waitcnt(0x0F78);   // vmcnt(8): K0 landed; K1,V0 in flight
    __builtin_amdgcn_s_barrier();
    __builtin_amdgcn_sched_barrier(0);
#pragma unroll
    for (int ks = 0; ks < 8; ++ks)
#pragma unroll
      for (int nt = 0; nt < 4; ++nt) {
        bf16x8 kf = *(const bf16x8*)&Ksh[0][(nt >> 1) * 8192 +
            ((ks * 4 + quad) * 32 + (nt & 1) * 16 + l16) * 8];
        s_prev[nt] = MFMA16(aq[ks], kf, s_prev[nt]);
      }
    __builtin_amdgcn_sched_barrier(0);
    __builtin_amdgcn_s_waitcnt(0xC07F);   // lgkmcnt(0)
    __builtin_amdgcn_s_barrier();
    __builtin_amdgcn_sched_barrier(0);
    // issue K(2) -> Ksh[0] (K0 consumed), then V(1) -> Vsh[1]
#pragma unroll
    for (int i = 0; i < 4; ++i)
      gl_lds16(ktb + (size_t)2 * 16384 + stoff + i * 4096, &Ksh[0][stoff + i * 4096]);
    __builtin_amdgcn_sched_barrier(0);
#pragma unroll
    for (int i = 0; i < 4; ++i)
      gl_lds16(vtb + (size_t)1 * 16384 + stoff + i * 4096, &Vsh[1][stoff + i * 4096]);
  }

  // ---- main loop: QK(it) || softmax(it-1)+PV(it-1) ----
  for (int it = 1; it < niter; ++it) {
    const int p = it & 1;
    // acquire: [K(it):4, V(it-1):4, K(it+1):4, V(it):4] -> vmcnt(8)
    // (last iter: V(it) was not issued -> queue is 12 deep -> vmcnt(4))
    __builtin_amdgcn_sched_barrier(0);
    if (it == niter - 1) __builtin_amdgcn_s_waitcnt(0x0F74);   // vmcnt(4)
    else                 __builtin_amdgcn_s_waitcnt(0x0F78);   // vmcnt(8)
    __builtin_amdgcn_s_barrier();
    __builtin_amdgcn_sched_barrier(0);

    // QK(it) on Ksh[p] — independent of softmax/PV(it-1) below (same region,
    // separate register streams: scheduler interleaves freely)
    f32x4 s_cur[4] = {fzero, fzero, fzero, fzero};
#pragma unroll
    for (int ks = 0; ks < 8; ++ks)
#pragma unroll
      for (int nt = 0; nt < 4; ++nt) {
        bf16x8 kf = *(const bf16x8*)&Ksh[p][(nt >> 1) * 8192 +
            ((ks * 4 + quad) * 32 + (nt & 1) * 16 + l16) * 8];
        s_cur[nt] = MFMA16(aq[ks], kf, s_cur[nt]);
      }

    // softmax(it-1) -> wave-private Psh
#pragma unroll
    for (int nt = 0; nt < 4; ++nt) {
      float ac = SLOPE2 * (float)(kvb + (it - 1) * 64 + nt * 16 + l16);
#pragma unroll
      for (int r = 0; r < 4; ++r) {
        float a0 = ac - arb - SLOPE2 * (float)r;
        float pv = __builtin_amdgcn_exp2f(fmaf(s_prev[nt][r], SCALE2, a0));
        Psh[w][(quad * 4 + r) * PSTR + nt * 16 + l16] = f2bf(pv);
      }
    }

    // PV(it-1) on Vsh[1-p] + rowsum (lgkm orders wave-private write->read)
    bf16x8 pf0 = *(const bf16x8*)&Psh[w][l16 * PSTR + quad * 8];
    bf16x8 pf1 = *(const bf16x8*)&Psh[w][l16 * PSTR + 32 + quad * 8];
    lac = MFMA16(pf0, vones, lac);
    lac = MFMA16(pf1, vones, lac);
#pragma unroll
    for (int ht = 0; ht < 16; ++ht) {
      bf16x8 vf0 = *(const bf16x8*)&Vsh[1 - p][(quad * 256 + ht * 16 + l16) * 8];
      bf16x8 vf1 = *(const bf16x8*)&Vsh[1 - p][8192 + (quad * 256 + ht * 16 + l16) * 8];
      O[ht] = MFMA16(pf0, vf0, O[ht]);
      O[ht] = MFMA16(pf1, vf1, O[ht]);
    }

    // roll score regs (static indexing)
#pragma unroll
    for (int nt = 0; nt < 4; ++nt) s_prev[nt] = s_cur[nt];

    // release: drain LDS ops, barrier -> Ksh[p], Vsh[1-p] free for overwrite
    __builtin_amdgcn_sched_barrier(0);
    __builtin_amdgcn_s_waitcnt(0xC07F);   // lgkmcnt(0) only
    __builtin_amdgcn_s_barrier();
    __builtin_amdgcn_sched_barrier(0);

    // issue K(it+2) -> Ksh[p] (K(it) consumed), then V(it+1) -> Vsh[1-p]
    // (V(it-1) consumed). Order K-then-V preserves the vmcnt ledger.
    if (it < niter - 2) {
      const ushort* kg = ktb + (size_t)(it + 2) * 16384;
#pragma unroll
      for (int i = 0; i < 4; ++i)
        gl_lds16(kg + stoff + i * 4096, &Ksh[p][stoff + i * 4096]);
    }
    __builtin_amdgcn_sched_barrier(0);
    if (it < niter - 1) {
      const ushort* vg = vtb + (size_t)(it + 1) * 16384;
#pragma unroll
      for (int i = 0; i < 4; ++i)
        gl_lds16(vg + stoff + i * 4096, &Vsh[1 - p][stoff + i * 4096]);
    }
  }

  // ---- tail: softmax(15)+PV(15) on Vsh[1] ----
  {
    __builtin_amdgcn_sched_barrier(0);
    __builtin_amdgcn_s_waitcnt(0x0070);   // vmcnt(0) lgkm(0): V(15) landed
    __builtin_amdgcn_s_barrier();
    __builtin_amdgcn_sched_barrier(0);
#pragma unroll
    for (int nt = 0; nt < 4; ++nt) {
      float ac = SLOPE2 * (float)(kvb + (niter - 1) * 64 + nt * 16 + l16);
#pragma unroll
      for (int r = 0; r < 4; ++r) {
        float a0 = ac - arb - SLOPE2 * (float)r;
        float pv = __builtin_amdgcn_exp2f(fmaf(s_prev[nt][r], SCALE2, a0));
        Psh[w][(quad * 4 + r) * PSTR + nt * 16 + l16] = f2bf(pv);
      }
    }
    bf16x8 pf0 = *(const bf16x8*)&Psh[w][l16 * PSTR + quad * 8];
    bf16x8 pf1 = *(const bf16x8*)&Psh[w][l16 * PSTR + 32 + quad * 8];
    lac = MFMA16(pf0, vones, lac);
    lac = MFMA16(pf1, vones, lac);
#pragma unroll
    for (int ht = 0; ht < 16; ++ht) {
      bf16x8 vf0 = *(const bf16x8*)&Vsh[1][(quad * 256 + ht * 16 + l16) * 8];
      bf16x8 vf1 = *(const bf16x8*)&Vsh[1][8192 + (quad * 256 + ht * 16 + l16) * 8];
      O[ht] = MFMA16(pf0, vf0, O[ht]);
      O[ht] = MFMA16(pf1, vf1, O[ht]);
    }
  }

  // epilogue: unnormalized O-partial + l-partial
  float* od = (sp == 0) ? out : o1;
  float* ob = od + ((size_t)(b * T_) + q0 + w * 16) * H_;
#pragma unroll
  for (int r = 0; r < 4; ++r) {
    int row = quad * 4 + r;
#pragma unroll
    for (int ht = 0; ht < 16; ++ht)
      ob[(size_t)row * H_ + ht * 16 + l16] = O[ht][r];
  }
  if (l16 == 0) {
#pragma unroll
    for (int r = 0; r < 4; ++r)
      lpart[(size_t)(sp * B_ + b) * T_ + q0 + w * 16 + quad * 4 + r] = lac[r];
  }
}

// ---- combine: out = (O0 + O1) / (l0 + l1) ----
__global__ void combine_kernel(float* __restrict__ out, const float* __restrict__ o1,
                               const float* __restrict__ lpart) {
  int idx = blockIdx.x * 256 + threadIdx.x;   // over B*T*H/4
  int row = idx >> 6;
  float inv = 1.0f / (lpart[row] + lpart[B_ * T_ + row]);
  float4 a = ((const float4*)out)[idx];
  float4 c = ((const float4*)o1)[idx];
  a.x = (a.x + c.x) * inv; a.y = (a.y + c.y) * inv;
  a.z = (a.z + c.z) * inv; a.w = (a.w + c.w) * inv;
  ((float4*)out)[idx] = a;
}

extern "C" void kernel_launch(void* const* d_in, const int* in_sizes, int n_in,
                              void* d_out, int out_size, void* d_ws, size_t ws_size,
                              hipStream_t stream) {
  const float* q = (const float*)d_in[0];
  const float* k = (const float*)d_in[1];
  const float* v = (const float*)d_in[2];
  float* out = (float*)d_out;

  ushort* kt = (ushort*)d_ws;
  ushort* vt = kt + ELEMS;
  float* o1 = (float*)(vt + ELEMS);
  float* lpart = o1 + ELEMS;            // 2*B*T floats

  prep_kernel<<<dim3(2048), 256, 0, stream>>>(k, v, kt, vt);
  attn_kernel<<<dim3(B_, T_ / 128, 2), 512, 0, stream>>>(q, kt, vt, out, o1, lpart);
  combine_kernel<<<dim3((B_ * T_ * H_ / 4) / 256), 256, 0, stream>>>(out, o1, lpart);
}